// Round 9
// baseline (2002.993 us; speedup 1.0000x reference)
//
#include <hip/hip_runtime.h>
#include <hip/hip_bf16.h>
#include <cstddef>

// ---------------------------------------------------------------------------
// GCN 2-layer forward.
//  h1 = relu(Agg(x @ W1) + b1);  out = log_softmax(Agg(h1 @ W2) + b2)
//  t = dinv * (z @ W) (bf16 gather table); out_i = di*(t_i + sum_e w_e t_src) + b
// Round 9: bucket-local LDS aggregation. 32-node buckets (NB=1563); the agg
// kernels read the bucket-partitioned edge list (part) directly and
// accumulate into an LDS fp32 accumulator (32x128 = 16.6 KB) via ds_add —
// the per-node CSR reorder (bucket_csr) is GONE. gemm1 is unscaled and fused
// into the scatter launch (off critical path); dinv + table scaling happen
// in bucket_deg's epilogue. h1 stored bf16. agg2 same scheme + fused lsm.
// ---------------------------------------------------------------------------

#define DIN 256
#define DH  128
#define DOUT 64
#define NPB 32         // nodes per bucket -> NB = ceil(n/32) = 1563
#define NBMAX 2048
#define PBLK 500       // edge-chunk blocks for hist/scatter

typedef __bf16 bf16x8 __attribute__((ext_vector_type(8)));
typedef float f32x4 __attribute__((ext_vector_type(4)));

__device__ __forceinline__ float bflo(unsigned u) { return __uint_as_float(u << 16); }
__device__ __forceinline__ float bfhi(unsigned u) { return __uint_as_float(u & 0xffff0000u); }
__device__ __forceinline__ unsigned short f2bf(float f) {
    unsigned u = __float_as_uint(f);
    unsigned r = (u + 0x7fffu + ((u >> 16) & 1u)) >> 16;   // round-nearest-even
    return (unsigned short)r;
}

// Pass 1 (fused): blocks [0,P) histogram col[] into bh[p][NB]; blocks >= P
// transpose+convert weights.
__launch_bounds__(256)
__global__ void hist_prep_kernel(const int* __restrict__ col, int* __restrict__ bh,
                                 int E, int Ec, int NB, int P,
                                 const float* __restrict__ W1, const float* __restrict__ W2,
                                 unsigned short* __restrict__ wt1, unsigned short* __restrict__ wt2) {
    __shared__ int hist[NBMAX];
    int p = blockIdx.x, t = threadIdx.x;
    if (p >= P) {
        int i = (p - P) * 256 + t;
        if (i < DH * DIN) {                       // wt1 [128][256]
            int nn = i >> 8, k = i & 255;
            wt1[i] = f2bf(W1[k * DH + nn]);
        } else {
            int j = i - DH * DIN;
            if (j < DOUT * DH) {                  // wt2 [64][128]
                int nn = j >> 7, k = j & 127;
                wt2[j] = f2bf(W2[k * DOUT + nn]);
            }
        }
        return;
    }
    for (int b = t; b < NB; b += 256) hist[b] = 0;
    __syncthreads();
    int s = p * Ec, e = min(s + Ec, E);
    for (int i = s + t; i < e; i += 256) atomicAdd(&hist[col[i] >> 5], 1);
    __syncthreads();
    for (int b = t; b < NB; b += 256) bh[p * NB + b] = hist[b];
}

// Pass 2: per-bucket column scan over the P blocks (exclusive, in place).
__launch_bounds__(512)
__global__ void colscan_kernel(int* __restrict__ bh, int* __restrict__ btotal,
                               int P, int NB) {
    __shared__ int arr[512];
    int b = blockIdx.x, t = threadIdx.x;
    int v = (t < P) ? bh[t * NB + b] : 0;
    arr[t] = v;
    __syncthreads();
    for (int off = 1; off < 512; off <<= 1) {
        int u = (t >= off) ? arr[t - off] : 0;
        __syncthreads();
        arr[t] += u;
        __syncthreads();
    }
    if (t < P) bh[t * NB + b] = arr[t] - v;       // exclusive
    if (t == P - 1) btotal[b] = arr[t];
}

// Pass 2b: exclusive scan of btotal (up to 2048 entries, 2 per thread)
// -> bbase[0..NB].
__launch_bounds__(1024)
__global__ void basescan_kernel(const int* __restrict__ btotal, int* __restrict__ bbase,
                                int NB) {
    __shared__ int arr[1024];
    int t = threadIdx.x;
    int v0 = (2 * t < NB) ? btotal[2 * t] : 0;
    int v1 = (2 * t + 1 < NB) ? btotal[2 * t + 1] : 0;
    int s = v0 + v1;
    arr[t] = s;
    __syncthreads();
    for (int off = 1; off < 1024; off <<= 1) {
        int u = (t >= off) ? arr[t - off] : 0;
        __syncthreads();
        arr[t] += u;
        __syncthreads();
    }
    int excl = arr[t] - s;
    if (2 * t <= NB) bbase[2 * t] = excl;
    if (2 * t + 1 <= NB) bbase[2 * t + 1] = excl + v0;
}

// MFMA GEMM body: C[r][:] = bf16( [scale[r]] * (A[r][:K] @ B) ), B transposed
// bf16 Wt[M][K]. 64 rows x full M per block, 4 waves. A fp32 or bf16.
template <int K, int M, bool ABF16, bool SCALED>
__device__ __forceinline__ void gemm_body(const void* __restrict__ Araw,
                                          const unsigned short* __restrict__ Wt,
                                          const float* __restrict__ scale,
                                          unsigned short* __restrict__ C,
                                          int N, int bid, int tid, char* sraw, float* sdv) {
    constexpr int BK = 64, LD = BK + 8;
    constexpr int WN = M / 4, NTL = WN / 16, CLD = M + 8;
    unsigned short* As = (unsigned short*)sraw;           // [64][LD]
    unsigned short* Bs = As + 64 * LD;                    // [M][LD]
    const int row0 = bid * 64;
    const int lane = tid & 63;
    const int quad = lane >> 4, r16 = lane & 15;
    const int n0 = (tid >> 6) * WN;

    if (SCALED && tid < 64) {
        int r = row0 + tid;
        sdv[tid] = (r < N) ? scale[r] : 0.0f;
    }

    f32x4 acc[4][NTL];
#pragma unroll
    for (int mt = 0; mt < 4; ++mt)
#pragma unroll
        for (int nt = 0; nt < NTL; ++nt)
            acc[mt][nt] = (f32x4){0.f, 0.f, 0.f, 0.f};

    for (int k0 = 0; k0 < K; k0 += BK) {
        if (ABF16) {
            const unsigned short* A = (const unsigned short*)Araw;
#pragma unroll
            for (int j = 0; j < 2; ++j) {
                int idx = tid + j * 256;
                int m = idx >> 3;
                int q = idx & 7;
                int gr = row0 + m;
                uint4 v = make_uint4(0, 0, 0, 0);
                if (gr < N) v = *(const uint4*)&A[(size_t)gr * K + k0 + q * 8];
                *(uint4*)&As[m * LD + q * 8] = v;
            }
        } else {
            const float* A = (const float*)Araw;
#pragma unroll
            for (int j = 0; j < 4; ++j) {
                int idx = tid + j * 256;
                int m = idx >> 4;
                int q = idx & 15;
                int gr = row0 + m;
                float4 v = make_float4(0.f, 0.f, 0.f, 0.f);
                if (gr < N) v = *(const float4*)&A[(size_t)gr * K + k0 + q * 4];
                ushort4 s4;
                s4.x = f2bf(v.x); s4.y = f2bf(v.y); s4.z = f2bf(v.z); s4.w = f2bf(v.w);
                *(ushort4*)&As[m * LD + q * 4] = s4;
            }
        }
#pragma unroll
        for (int j = 0; j < M * 8 / 256; ++j) {
            int idx = tid + j * 256;
            int nn = idx >> 3;
            int q = idx & 7;
            uint4 v = *(const uint4*)&Wt[(size_t)nn * K + k0 + q * 8];
            *(uint4*)&Bs[nn * LD + q * 8] = v;
        }
        __syncthreads();
#pragma unroll
        for (int ks = 0; ks < BK / 32; ++ks) {
            bf16x8 af[4], bfr[NTL];
#pragma unroll
            for (int nt = 0; nt < NTL; ++nt)
                bfr[nt] = *(const bf16x8*)&Bs[(n0 + nt * 16 + r16) * LD + ks * 32 + quad * 8];
#pragma unroll
            for (int mt = 0; mt < 4; ++mt)
                af[mt] = *(const bf16x8*)&As[(mt * 16 + r16) * LD + ks * 32 + quad * 8];
#pragma unroll
            for (int mt = 0; mt < 4; ++mt)
#pragma unroll
                for (int nt = 0; nt < NTL; ++nt)
                    acc[mt][nt] = __builtin_amdgcn_mfma_f32_16x16x32_bf16(
                        af[mt], bfr[nt], acc[mt][nt], 0, 0, 0);
        }
        __syncthreads();
    }
    unsigned short* Cs = (unsigned short*)sraw;           // [64][CLD]
#pragma unroll
    for (int mt = 0; mt < 4; ++mt)
#pragma unroll
        for (int i = 0; i < 4; ++i) {
            int r = mt * 16 + quad * 4 + i;
            float sc = SCALED ? sdv[r] : 1.0f;
#pragma unroll
            for (int nt = 0; nt < NTL; ++nt)
                Cs[r * CLD + n0 + nt * 16 + r16] = f2bf(acc[mt][nt][i] * sc);
        }
    __syncthreads();
#pragma unroll
    for (int j = 0; j < 64 * M / 8 / 256; ++j) {
        int idx = tid + j * 256;
        int r = idx / (M / 8);
        int q = idx % (M / 8);
        int gr = row0 + r;
        if (gr < N) {
            uint4 v = *(const uint4*)&Cs[r * CLD + q * 8];
            *(uint4*)&C[(size_t)gr * M + q * 8] = v;
        }
    }
}

// Fused: blocks [0,P) scatter edges to bucket order (LDS cursors);
// blocks >= P run gemm1 (UNSCALED: table scaled later by bucket_deg).
__launch_bounds__(256)
__global__ void gemm1_scatter_kernel(const float* __restrict__ x,
                                     const unsigned short* __restrict__ wt1,
                                     unsigned short* __restrict__ xw1, int N,
                                     const int* __restrict__ row, const int* __restrict__ col,
                                     const float* __restrict__ w, const int* __restrict__ bh,
                                     const int* __restrict__ bbase, int2* __restrict__ part,
                                     int E, int Ec, int NB, int P) {
    __shared__ __align__(16) char sraw[(64 + DH) * (64 + 8) * 2];
    __shared__ float sdv[64];
    int tid = threadIdx.x;
    if ((int)blockIdx.x < P) {
        int* cur = (int*)sraw;                    // NB ints (<= 2048)
        int p = blockIdx.x;
        for (int b = tid; b < NB; b += 256) cur[b] = bbase[b] + bh[p * NB + b];
        __syncthreads();
        int s = p * Ec, e = min(s + Ec, E);
        for (int i = s + tid; i < e; i += 256) {
            int c = col[i];
            int r = row[i];
            int b = c >> 5;
            int pos = atomicAdd(&cur[b], 1);      // LDS atomic
            part[pos] = make_int2(r | ((c & 31) << 16), __float_as_int(w[i]));
        }
    } else {
        gemm_body<DIN, DH, false, false>(x, wt1, nullptr, xw1, N,
                                         blockIdx.x - P, tid, sraw, sdv);
    }
}

// Pass 4: per bucket: wsum -> dinv, then scale the bucket's xw1 rows by dinv
// (in place). part is read once (8B/edge), no reorder write.
__launch_bounds__(256)
__global__ void bucket_deg_kernel(const int2* __restrict__ part, const int* __restrict__ bbase,
                                  float* __restrict__ dinv, unsigned* __restrict__ xw1, int n) {
    __shared__ float wsum[NPB];
    __shared__ float sdv[NPB];
    int b = blockIdx.x, t = threadIdx.x;
    if (t < NPB) wsum[t] = 0.0f;
    __syncthreads();
    int s = bbase[b], e = bbase[b + 1];
    for (int i = s + t; i < e; i += 256) {
        int2 rec = part[i];
        atomicAdd(&wsum[rec.x >> 16], __int_as_float(rec.y));
    }
    __syncthreads();
    if (t < NPB) {
        int g = b * NPB + t;
        float di = 0.0f;
        if (g < n) {
            di = rsqrtf(1.0f + wsum[t]);          // deg >= 1 (self-loop)
            dinv[g] = di;
        }
        sdv[t] = di;
    }
    __syncthreads();
    for (int idx = t; idx < NPB * 64; idx += 256) {
        int node = idx >> 6, u = idx & 63;
        int g = b * NPB + node;
        if (g < n) {
            unsigned v = xw1[(size_t)g * 64 + u];
            float di = sdv[node];
            unsigned lo = f2bf(di * bflo(v));
            unsigned hi = f2bf(di * bfhi(v));
            xw1[(size_t)g * 64 + u] = lo | (hi << 16);
        }
    }
}

// Layer-1 aggregation, bucket-local LDS accumulate.
// Block = 1 bucket (32 nodes). Edge loop: each wave takes a contiguous
// quarter of the bucket's edges; per edge one wave-wide row gather (lane =
// bf16x2 feature pair) + 2 LDS atomic adds. Unroll 4 (4 gathers in flight).
// Epilogue: h1[g] = bf16(relu(di*(t_i + acc) + b1)) written coalesced.
__launch_bounds__(256)
__global__ void agg1_bucket_kernel(const unsigned* __restrict__ xw1,   // bf16 [n][128] scaled
                                   const int2* __restrict__ part,      // (src|cl<<16, raw w)
                                   const int* __restrict__ bbase,
                                   const float* __restrict__ dinv,
                                   const float* __restrict__ b1,       // fp32 [128]
                                   unsigned* __restrict__ h1, int n) { // bf16 [n][128]
    __shared__ float acc[NPB * 130];
    __shared__ float sdv[NPB];
    const int b = blockIdx.x, tid = threadIdx.x;
    for (int i = tid; i < NPB * 130; i += 256) acc[i] = 0.0f;
    if (tid < NPB) {
        int g = b * NPB + tid;
        sdv[tid] = (g < n) ? dinv[g] : 0.0f;
    }
    __syncthreads();
    const int s = bbase[b], e = bbase[b + 1];
    const int len = e - s;
    const int w = tid >> 6, lane = tid & 63;
    const int q = (len + 3) >> 2;
    int p = s + w * q;
    const int p1 = min(p + q, e);
    for (; p + 4 <= p1; p += 4) {
        int2 r0 = part[p], r1 = part[p + 1], r2 = part[p + 2], r3 = part[p + 3];
        unsigned v0 = xw1[(size_t)(r0.x & 0xffff) * 64 + lane];
        unsigned v1 = xw1[(size_t)(r1.x & 0xffff) * 64 + lane];
        unsigned v2 = xw1[(size_t)(r2.x & 0xffff) * 64 + lane];
        unsigned v3 = xw1[(size_t)(r3.x & 0xffff) * 64 + lane];
        float w0 = __int_as_float(r0.y), w1 = __int_as_float(r1.y);
        float w2 = __int_as_float(r2.y), w3 = __int_as_float(r3.y);
        int c0 = (r0.x >> 16) * 130 + 2 * lane;
        int c1 = (r1.x >> 16) * 130 + 2 * lane;
        int c2 = (r2.x >> 16) * 130 + 2 * lane;
        int c3 = (r3.x >> 16) * 130 + 2 * lane;
        atomicAdd(&acc[c0], w0 * bflo(v0)); atomicAdd(&acc[c0 + 1], w0 * bfhi(v0));
        atomicAdd(&acc[c1], w1 * bflo(v1)); atomicAdd(&acc[c1 + 1], w1 * bfhi(v1));
        atomicAdd(&acc[c2], w2 * bflo(v2)); atomicAdd(&acc[c2 + 1], w2 * bfhi(v2));
        atomicAdd(&acc[c3], w3 * bflo(v3)); atomicAdd(&acc[c3 + 1], w3 * bfhi(v3));
    }
    for (; p < p1; ++p) {
        int2 r0 = part[p];
        unsigned v0 = xw1[(size_t)(r0.x & 0xffff) * 64 + lane];
        float w0 = __int_as_float(r0.y);
        int c0 = (r0.x >> 16) * 130 + 2 * lane;
        atomicAdd(&acc[c0], w0 * bflo(v0)); atomicAdd(&acc[c0 + 1], w0 * bfhi(v0));
    }
    __syncthreads();
    for (int idx = tid; idx < NPB * 64; idx += 256) {
        int node = idx >> 6, u = idx & 63;
        int g = b * NPB + node;
        if (g < n) {
            unsigned tv = xw1[(size_t)g * 64 + u];
            float di = sdv[node];
            float2 bb = ((const float2*)b1)[u];
            float f0 = fmaxf(di * (bflo(tv) + acc[node * 130 + 2 * u]) + bb.x, 0.0f);
            float f1 = fmaxf(di * (bfhi(tv) + acc[node * 130 + 2 * u + 1]) + bb.y, 0.0f);
            h1[(size_t)g * 64 + u] = (unsigned)f2bf(f0) | ((unsigned)f2bf(f1) << 16);
        }
    }
}

__launch_bounds__(256)
__global__ void gemm2_kernel(const unsigned short* __restrict__ h1,
                             const unsigned short* __restrict__ wt2,
                             const float* __restrict__ dinv,
                             unsigned short* __restrict__ xw2, int N) {
    __shared__ __align__(16) char sraw[(64 + DOUT) * (64 + 8) * 2];
    __shared__ float sdv[64];
    gemm_body<DH, DOUT, true, true>(h1, wt2, dinv, xw2, N,
                                    blockIdx.x, threadIdx.x, sraw, sdv);
}

// Layer-2 aggregation, bucket-local LDS accumulate + fused log_softmax.
// Row = 32 uints (64 bf16): half-wave per edge (2 edges/step, unroll 4).
__launch_bounds__(256)
__global__ void agg2_bucket_kernel(const unsigned* __restrict__ xw2,   // bf16 [n][64] scaled
                                   const int2* __restrict__ part,
                                   const int* __restrict__ bbase,
                                   const float* __restrict__ dinv,
                                   const float* __restrict__ b2,       // fp32 [64]
                                   float* __restrict__ out, int n) {   // fp32 [n][64]
    __shared__ float acc[NPB * 66];
    __shared__ float sdv[NPB];
    const int b = blockIdx.x, tid = threadIdx.x;
    for (int i = tid; i < NPB * 66; i += 256) acc[i] = 0.0f;
    if (tid < NPB) {
        int g = b * NPB + tid;
        sdv[tid] = (g < n) ? dinv[g] : 0.0f;
    }
    __syncthreads();
    const int s = bbase[b], e = bbase[b + 1];
    const int len = e - s;
    const int w = tid >> 6, lane = tid & 63;
    const int half = lane >> 5, sub = lane & 31;
    const int q = (len + 3) >> 2;
    int p = s + w * q;
    const int p1 = min(p + q, e);
    for (; p + 8 <= p1; p += 8) {
        int2 r0 = part[p + half],     r1 = part[p + 2 + half];
        int2 r2 = part[p + 4 + half], r3 = part[p + 6 + half];
        unsigned v0 = xw2[(size_t)(r0.x & 0xffff) * 32 + sub];
        unsigned v1 = xw2[(size_t)(r1.x & 0xffff) * 32 + sub];
        unsigned v2 = xw2[(size_t)(r2.x & 0xffff) * 32 + sub];
        unsigned v3 = xw2[(size_t)(r3.x & 0xffff) * 32 + sub];
        float w0 = __int_as_float(r0.y), w1 = __int_as_float(r1.y);
        float w2 = __int_as_float(r2.y), w3 = __int_as_float(r3.y);
        int c0 = (r0.x >> 16) * 66 + 2 * sub;
        int c1 = (r1.x >> 16) * 66 + 2 * sub;
        int c2 = (r2.x >> 16) * 66 + 2 * sub;
        int c3 = (r3.x >> 16) * 66 + 2 * sub;
        atomicAdd(&acc[c0], w0 * bflo(v0)); atomicAdd(&acc[c0 + 1], w0 * bfhi(v0));
        atomicAdd(&acc[c1], w1 * bflo(v1)); atomicAdd(&acc[c1 + 1], w1 * bfhi(v1));
        atomicAdd(&acc[c2], w2 * bflo(v2)); atomicAdd(&acc[c2 + 1], w2 * bfhi(v2));
        atomicAdd(&acc[c3], w3 * bflo(v3)); atomicAdd(&acc[c3 + 1], w3 * bfhi(v3));
    }
    for (; p + 2 <= p1; p += 2) {
        int2 r0 = part[p + half];
        unsigned v0 = xw2[(size_t)(r0.x & 0xffff) * 32 + sub];
        float w0 = __int_as_float(r0.y);
        int c0 = (r0.x >> 16) * 66 + 2 * sub;
        atomicAdd(&acc[c0], w0 * bflo(v0)); atomicAdd(&acc[c0 + 1], w0 * bfhi(v0));
    }
    if (p < p1 && half == 0) {
        int2 r0 = part[p];
        unsigned v0 = xw2[(size_t)(r0.x & 0xffff) * 32 + sub];
        float w0 = __int_as_float(r0.y);
        int c0 = (r0.x >> 16) * 66 + 2 * sub;
        atomicAdd(&acc[c0], w0 * bflo(v0)); atomicAdd(&acc[c0 + 1], w0 * bfhi(v0));
    }
    __syncthreads();
    // epilogue: wave w handles nodes [w*8, w*8+8); lane = feature.
    const unsigned short* t2 = (const unsigned short*)xw2;
#pragma unroll 1
    for (int r = 0; r < 8; ++r) {
        int node = w * 8 + r;
        int g = b * NPB + node;
        if (g >= n) continue;
        float di = sdv[node];
        float tv = __uint_as_float((unsigned)t2[(size_t)g * 64 + lane] << 16);
        float val = di * (tv + acc[node * 66 + lane]) + b2[lane];
        float m = val;
#pragma unroll
        for (int off = 32; off > 0; off >>= 1) m = fmaxf(m, __shfl_xor(m, off));
        float sm = __expf(val - m);
#pragma unroll
        for (int off = 32; off > 0; off >>= 1) sm += __shfl_xor(sm, off);
        out[(size_t)g * 64 + lane] = val - m - __logf(sm);
    }
}

extern "C" void kernel_launch(void* const* d_in, const int* in_sizes, int n_in,
                              void* d_out, int out_size, void* d_ws, size_t ws_size,
                              hipStream_t stream) {
    const float* x  = (const float*)d_in[0];
    const int*   ei = (const int*)d_in[1];
    const float* ew = (const float*)d_in[2];
    const float* W1 = (const float*)d_in[3];
    const float* b1 = (const float*)d_in[4];
    const float* W2 = (const float*)d_in[5];
    const float* b2 = (const float*)d_in[6];
    float* out = (float*)d_out;

    const int n = in_sizes[0] / DIN;      // 50000
    const int E = in_sizes[2];            // 1600000
    const int* row = ei;                  // edge_index[0] (source)
    const int* col = ei + E;              // edge_index[1] (target)

    const int NB = (n + NPB - 1) / NPB;   // 1563 buckets
    const int P  = PBLK;                  // 500 edge-chunk blocks
    const int Ec = (E + P - 1) / P;       // 3200 edges/block

    char* ptr = (char*)d_ws;
    auto alloc = [&](size_t bytes) -> void* {
        void* r = (void*)ptr;
        ptr += (bytes + 255) & ~(size_t)255;
        return r;
    };
    int*   bh     = (int*)  alloc((size_t)P * NB * 4);       // 3.1 MB
    int*   btotal = (int*)  alloc((size_t)NB * 4);
    int*   bbase  = (int*)  alloc((size_t)(NB + 1) * 4);
    float* dinv   = (float*)alloc((size_t)n * 4);
    int2*  part   = (int2*) alloc((size_t)E * 8);            // bucket-partitioned edges
    unsigned short* xw1 = (unsigned short*)alloc((size_t)n * DH * 2);   // bf16 [n][128]
    unsigned short* h1  = (unsigned short*)alloc((size_t)n * DH * 2);   // bf16 [n][128]
    unsigned short* xw2 = (unsigned short*)alloc((size_t)n * DOUT * 2); // bf16 [n][64]
    unsigned short* wt1 = (unsigned short*)alloc((size_t)DH * DIN * 2);
    unsigned short* wt2 = (unsigned short*)alloc((size_t)DOUT * DH * 2);

    const int nb_g = (n + 63) / 64;       // 782
    const int PREPB = (DH * DIN + DOUT * DH + 255) / 256;    // 160

    hist_prep_kernel<<<P + PREPB, 256, 0, stream>>>(col, bh, E, Ec, NB, P, W1, W2, wt1, wt2);
    colscan_kernel<<<NB, 512, 0, stream>>>(bh, btotal, P, NB);
    basescan_kernel<<<1, 1024, 0, stream>>>(btotal, bbase, NB);
    gemm1_scatter_kernel<<<P + nb_g, 256, 0, stream>>>(
        x, wt1, xw1, n, row, col, ew, bh, bbase, part, E, Ec, NB, P);
    bucket_deg_kernel<<<NB, 256, 0, stream>>>(part, bbase, dinv, (unsigned*)xw1, n);
    agg1_bucket_kernel<<<NB, 256, 0, stream>>>((const unsigned*)xw1, part, bbase,
                                               dinv, b1, (unsigned*)h1, n);
    gemm2_kernel<<<nb_g, 256, 0, stream>>>(h1, wt2, dinv, xw2, n);
    agg2_bucket_kernel<<<NB, 256, 0, stream>>>((const unsigned*)xw2, part, bbase,
                                               dinv, b2, out, n);
}